// Round 1
// baseline (94.557 us; speedup 1.0000x reference)
//
#include <hip/hip_runtime.h>
#include <hip/hip_bf16.h>
#include <math.h>

#define B_PAIRS 2048
#define N_ROWS  4096
#define D_DIM   256
#define INV_T   2.0f

typedef __attribute__((ext_vector_type(8))) short  short8;   // 8 x bf16
typedef __attribute__((ext_vector_type(4))) float  floatx4;

// ---- workspace layout ----
// [0, 2MB)            : zn (bf16, 4096 x 256)
// [2MB, 2MB+16KB)     : S[4096]   (fp32, sum_{j!=i} exp(sim_ij))
// [2MB+16KB, +16KB)   : pos[4096] (fp32, sim[i, i^2048])

__device__ __forceinline__ void async_copy16(const void* gsrc, void* ldst) {
    __builtin_amdgcn_global_load_lds(
        (__attribute__((address_space(1))) void*)gsrc,
        (__attribute__((address_space(3))) void*)ldst,
        16, 0, 0);
}

// ---------- kernel 1: row-normalize, fp32 -> bf16 ----------
__global__ void ntx_normalize(const float* __restrict__ z_i,
                              const float* __restrict__ z_j,
                              __hip_bfloat16* __restrict__ zn) {
    const int row = blockIdx.x;          // 0..4095
    const int tid = threadIdx.x;         // 0..255 (== D)
    const float* src = (row < B_PAIRS) ? (z_i + (size_t)row * D_DIM)
                                       : (z_j + (size_t)(row - B_PAIRS) * D_DIM);
    float v  = src[tid];
    float ss = v * v;
    #pragma unroll
    for (int off = 32; off > 0; off >>= 1) ss += __shfl_down(ss, off, 64);
    __shared__ float red[4];
    const int lane = tid & 63, w = tid >> 6;
    if (lane == 0) red[w] = ss;
    __syncthreads();
    if (tid == 0) red[0] = red[0] + red[1] + red[2] + red[3];
    __syncthreads();
    float norm = fmaxf(sqrtf(red[0]), 1e-8f);
    zn[(size_t)row * D_DIM + tid] = __float2bfloat16(v / norm);
}

// ---------- kernel 2: fused sim-tile GEMM + exp row-sum epilogue ----------
#define BM 128
#define BN 128
#define BK 32

__global__ __launch_bounds__(256)
void ntx_simtile(const __hip_bfloat16* __restrict__ zn,
                 float* __restrict__ S,
                 float* __restrict__ pos) {
    __shared__ __align__(16) __hip_bfloat16 As[BM * BK];
    __shared__ __align__(16) __hip_bfloat16 Bs[BN * BK];

    const int tid  = threadIdx.x;
    const int lane = tid & 63;
    const int w    = tid >> 6;           // wave 0..3
    const int wr   = w >> 1;             // wave row (0..1) -> 64-row strip
    const int wc   = w & 1;              // wave col (0..1) -> 64-col strip
    const int quad = lane >> 4;          // 0..3
    const int l16  = lane & 15;

    const int rowA0 = blockIdx.y * BM;
    const int rowB0 = blockIdx.x * BN;

    floatx4 acc[4][4];
    #pragma unroll
    for (int i = 0; i < 4; i++)
        #pragma unroll
        for (int j = 0; j < 4; j++)
            acc[i][j] = (floatx4){0.f, 0.f, 0.f, 0.f};

    for (int k0 = 0; k0 < D_DIM; k0 += BK) {
        // stage A (128x32) and B (128x32) tiles; 512 x 16B chunks each,
        // 256 threads x 2 chunks. LDS dest = linear chunk*16 => wave-uniform
        // base + lane*16 (required by global_load_lds).
        #pragma unroll
        for (int c = 0; c < 2; c++) {
            const int chunk = tid + c * 256;     // 0..511
            const int r  = chunk >> 2;           // tile row 0..127
            const int kc = chunk & 3;            // 16B chunk in row
            async_copy16(zn + ((size_t)(rowA0 + r) * D_DIM + k0 + kc * 8),
                         As + chunk * 8);
            async_copy16(zn + ((size_t)(rowB0 + r) * D_DIM + k0 + kc * 8),
                         Bs + chunk * 8);
        }
        __syncthreads();   // drains vmcnt before LDS use

        short8 afr[4], bfr[4];
        #pragma unroll
        for (int fi = 0; fi < 4; fi++) {
            const int ar = wr * 64 + fi * 16 + l16;
            afr[fi] = *(const short8*)(const void*)(As + ar * BK + quad * 8);
        }
        #pragma unroll
        for (int fj = 0; fj < 4; fj++) {
            const int brw = wc * 64 + fj * 16 + l16;
            bfr[fj] = *(const short8*)(const void*)(Bs + brw * BK + quad * 8);
        }
        #pragma unroll
        for (int fi = 0; fi < 4; fi++)
            #pragma unroll
            for (int fj = 0; fj < 4; fj++)
                acc[fi][fj] = __builtin_amdgcn_mfma_f32_16x16x32_bf16(
                    afr[fi], bfr[fj], acc[fi][fj], 0, 0, 0);
        __syncthreads();   // protect LDS from next iteration's staging
    }

    // epilogue: v = dot * (1/T); mask diagonal; capture pos; row-sum exp.
    // C/D layout (16x16): col = lane&15, row = quad*4 + reg  [m89]
    #pragma unroll
    for (int fi = 0; fi < 4; fi++) {
        float rs[4] = {0.f, 0.f, 0.f, 0.f};
        #pragma unroll
        for (int fj = 0; fj < 4; fj++) {
            const int jg = rowB0 + wc * 64 + fj * 16 + l16;
            #pragma unroll
            for (int reg = 0; reg < 4; reg++) {
                const int ig = rowA0 + wr * 64 + fi * 16 + quad * 4 + reg;
                const float v = acc[fi][fj][reg] * INV_T;
                if (jg == (ig ^ B_PAIRS)) pos[ig] = v;   // exactly once per row
                rs[reg] += (jg == ig) ? 0.f : __expf(v);
            }
        }
        #pragma unroll
        for (int reg = 0; reg < 4; reg++) {
            float r = rs[reg];
            r += __shfl_xor(r, 1, 16);
            r += __shfl_xor(r, 2, 16);
            r += __shfl_xor(r, 4, 16);
            r += __shfl_xor(r, 8, 16);
            if (l16 == 0) {
                const int ig = rowA0 + wr * 64 + fi * 16 + quad * 4 + reg;
                atomicAdd(&S[ig], r);
            }
        }
    }
}

// ---------- kernel 3: loss = mean(log S_i - pos_i) ----------
__global__ void ntx_finalize(const float* __restrict__ S,
                             const float* __restrict__ pos,
                             float* __restrict__ out) {
    const int tid = threadIdx.x;   // 256 threads
    float acc = 0.f;
    for (int i = tid; i < N_ROWS; i += 256)
        acc += logf(S[i]) - pos[i];
    #pragma unroll
    for (int off = 32; off > 0; off >>= 1) acc += __shfl_down(acc, off, 64);
    __shared__ float red[4];
    if ((tid & 63) == 0) red[tid >> 6] = acc;
    __syncthreads();
    if (tid == 0)
        out[0] = (red[0] + red[1] + red[2] + red[3]) / (float)N_ROWS;
}

extern "C" void kernel_launch(void* const* d_in, const int* in_sizes, int n_in,
                              void* d_out, int out_size, void* d_ws, size_t ws_size,
                              hipStream_t stream) {
    const float* z_i = (const float*)d_in[0];
    const float* z_j = (const float*)d_in[1];
    float* out = (float*)d_out;

    __hip_bfloat16* zn = (__hip_bfloat16*)d_ws;
    float* S   = (float*)((char*)d_ws + (size_t)N_ROWS * D_DIM * sizeof(__hip_bfloat16));
    float* pos = S + N_ROWS;

    hipMemsetAsync(S, 0, N_ROWS * sizeof(float), stream);  // S only; pos fully overwritten

    ntx_normalize<<<N_ROWS, D_DIM, 0, stream>>>(z_i, z_j, zn);

    dim3 grid(N_ROWS / BN, N_ROWS / BM);
    ntx_simtile<<<grid, 256, 0, stream>>>(zn, S, pos);

    ntx_finalize<<<1, 256, 0, stream>>>(S, pos, out);
}

// Round 2
// 81.477 us; speedup vs baseline: 1.1605x; 1.1605x over previous
//
#include <hip/hip_runtime.h>
#include <hip/hip_bf16.h>
#include <math.h>

#define B_PAIRS 2048
#define N_ROWS  4096
#define D_DIM   256
#define INV_T   2.0f

typedef __attribute__((ext_vector_type(8))) short  short8;   // 8 x bf16
typedef __attribute__((ext_vector_type(4))) float  floatx4;

// ---- workspace layout ----
// [0, 2MB)            : zn (bf16, 4096 x 256)
// [2MB, 2MB+16KB)     : S[4096]   (fp32, sum_{j!=i} exp(sim_ij))
// [2MB+16KB, +16KB)   : pos[4096] (fp32, sim[i, i^2048])

__device__ __forceinline__ void async_copy16(const void* gsrc, void* ldst) {
    __builtin_amdgcn_global_load_lds(
        (__attribute__((address_space(1))) void*)gsrc,
        (__attribute__((address_space(3))) void*)ldst,
        16, 0, 0);
}

// ---------- kernel 1: row-normalize fp32 -> bf16 (1 wave per row) ----------
// Also zero-inits S[row] (replaces a memset dispatch).
__global__ __launch_bounds__(256)
void ntx_normalize(const float* __restrict__ z_i,
                   const float* __restrict__ z_j,
                   __hip_bfloat16* __restrict__ zn,
                   float* __restrict__ S) {
    const int w    = threadIdx.x >> 6;               // wave 0..3
    const int lane = threadIdx.x & 63;
    const int row  = blockIdx.x * 4 + w;             // 0..4095
    const float* src = (row < B_PAIRS) ? (z_i + (size_t)row * D_DIM)
                                       : (z_j + (size_t)(row - B_PAIRS) * D_DIM);
    const float4 v = *(const float4*)(src + lane * 4);
    float ss = v.x * v.x + v.y * v.y + v.z * v.z + v.w * v.w;
    #pragma unroll
    for (int off = 32; off > 0; off >>= 1) ss += __shfl_xor(ss, off, 64);
    const float rn = 1.0f / fmaxf(sqrtf(ss), 1e-8f);
    union { short4 s4; __hip_bfloat16 h[4]; } u;
    u.h[0] = __float2bfloat16(v.x * rn);
    u.h[1] = __float2bfloat16(v.y * rn);
    u.h[2] = __float2bfloat16(v.z * rn);
    u.h[3] = __float2bfloat16(v.w * rn);
    *(short4*)(void*)(zn + (size_t)row * D_DIM + lane * 4) = u.s4;
    if (lane == 0) S[row] = 0.0f;
}

// ---------- kernel 2: upper-triangle sim tiles + exp row/col-sum epilogue ----------
#define BM 128
#define BN 128
#define BK 32
#define N_TILES 528            // 32 diag + 496 strictly-upper (32x32 tile grid)

__global__ __launch_bounds__(256)
void ntx_simtile(const __hip_bfloat16* __restrict__ zn,
                 float* __restrict__ S,
                 float* __restrict__ pos) {
    __shared__ __align__(16) __hip_bfloat16 As[BM * BK];
    __shared__ __align__(16) __hip_bfloat16 Bs[BN * BK];

    // linear block id -> upper-triangle (by, bx), bx >= by
    int t = blockIdx.x, by = 0, rowlen = 32;
    while (t >= rowlen) { t -= rowlen; by++; rowlen--; }
    const int bx = by + t;

    const int tid  = threadIdx.x;
    const int lane = tid & 63;
    const int w    = tid >> 6;           // wave 0..3
    const int wr   = w >> 1;             // wave row strip (0..1)
    const int wc   = w & 1;              // wave col strip (0..1)
    const int quad = lane >> 4;          // 0..3
    const int l16  = lane & 15;

    const int rowA0 = by * BM;
    const int rowB0 = bx * BN;
    const bool isDiag = (rowA0 == rowB0);
    const bool isPos  = (rowB0 == (rowA0 ^ B_PAIRS));

    floatx4 acc[4][4];
    #pragma unroll
    for (int i = 0; i < 4; i++)
        #pragma unroll
        for (int j = 0; j < 4; j++)
            acc[i][j] = (floatx4){0.f, 0.f, 0.f, 0.f};

    for (int k0 = 0; k0 < D_DIM; k0 += BK) {
        #pragma unroll
        for (int c = 0; c < 2; c++) {
            const int chunk = tid + c * 256;     // 0..511
            const int r  = chunk >> 2;           // tile row 0..127
            const int kc = chunk & 3;            // 16B chunk within row
            async_copy16(zn + ((size_t)(rowA0 + r) * D_DIM + k0 + kc * 8),
                         As + chunk * 8);
            async_copy16(zn + ((size_t)(rowB0 + r) * D_DIM + k0 + kc * 8),
                         Bs + chunk * 8);
        }
        __syncthreads();

        short8 afr[4], bfr[4];
        #pragma unroll
        for (int fi = 0; fi < 4; fi++) {
            const int ar = wr * 64 + fi * 16 + l16;
            afr[fi] = *(const short8*)(const void*)(As + ar * BK + quad * 8);
        }
        #pragma unroll
        for (int fj = 0; fj < 4; fj++) {
            const int brw = wc * 64 + fj * 16 + l16;
            bfr[fj] = *(const short8*)(const void*)(Bs + brw * BK + quad * 8);
        }
        #pragma unroll
        for (int fi = 0; fi < 4; fi++)
            #pragma unroll
            for (int fj = 0; fj < 4; fj++)
                acc[fi][fj] = __builtin_amdgcn_mfma_f32_16x16x32_bf16(
                    afr[fi], bfr[fj], acc[fi][fj], 0, 0, 0);
        __syncthreads();
    }

    // Epilogue. C/D layout (16x16): col = l16, row = quad*4 + reg.
    // Row sums -> S[rowA0 + ri]; for off-diag tiles, by symmetry the same
    // element also contributes to S[rowB0 + rj] (col sums).
    float cs[4] = {0.f, 0.f, 0.f, 0.f};   // per-lane col sums (col = wc*64+fj*16+l16)
    #pragma unroll
    for (int fi = 0; fi < 4; fi++) {
        float rs[4] = {0.f, 0.f, 0.f, 0.f};
        #pragma unroll
        for (int fj = 0; fj < 4; fj++) {
            const int rj = wc * 64 + fj * 16 + l16;
            #pragma unroll
            for (int reg = 0; reg < 4; reg++) {
                const int ri = wr * 64 + fi * 16 + quad * 4 + reg;
                const float v = acc[fi][fj][reg] * INV_T;
                const bool d = (ri == rj);
                if (isPos && d) {             // positive pair: sim[i, i^2048]
                    pos[rowA0 + ri] = v;
                    pos[rowB0 + rj] = v;      // symmetric partner, same value
                }
                const float e = (isDiag && d) ? 0.f : __expf(v);
                rs[reg] += e;
                cs[fj]  += e;
            }
        }
        #pragma unroll
        for (int reg = 0; reg < 4; reg++) {
            float r = rs[reg];
            r += __shfl_xor(r, 1, 16);
            r += __shfl_xor(r, 2, 16);
            r += __shfl_xor(r, 4, 16);
            r += __shfl_xor(r, 8, 16);
            if (l16 == 0)
                atomicAdd(&S[rowA0 + wr * 64 + fi * 16 + quad * 4 + reg], r);
        }
    }
    if (!isDiag) {
        #pragma unroll
        for (int fj = 0; fj < 4; fj++) {
            float c = cs[fj];
            c += __shfl_xor(c, 16, 64);      // reduce across quads
            c += __shfl_xor(c, 32, 64);
            if (quad == 0)
                atomicAdd(&S[rowB0 + wc * 64 + fj * 16 + l16], c);
        }
    }
}

// ---------- kernel 3: loss = mean(log S_i - pos_i) ----------
__global__ __launch_bounds__(1024)
void ntx_finalize(const float* __restrict__ S,
                  const float* __restrict__ pos,
                  float* __restrict__ out) {
    const int tid = threadIdx.x;   // 1024 threads
    float acc = 0.f;
    #pragma unroll
    for (int c = 0; c < 4; c++) {
        const int i = tid + c * 1024;
        acc += __logf(S[i]) - pos[i];
    }
    #pragma unroll
    for (int off = 32; off > 0; off >>= 1) acc += __shfl_down(acc, off, 64);
    __shared__ float red[16];
    if ((tid & 63) == 0) red[tid >> 6] = acc;
    __syncthreads();
    if (tid == 0) {
        float s = 0.f;
        #pragma unroll
        for (int k = 0; k < 16; k++) s += red[k];
        out[0] = s / (float)N_ROWS;
    }
}

extern "C" void kernel_launch(void* const* d_in, const int* in_sizes, int n_in,
                              void* d_out, int out_size, void* d_ws, size_t ws_size,
                              hipStream_t stream) {
    const float* z_i = (const float*)d_in[0];
    const float* z_j = (const float*)d_in[1];
    float* out = (float*)d_out;

    __hip_bfloat16* zn = (__hip_bfloat16*)d_ws;
    float* S   = (float*)((char*)d_ws + (size_t)N_ROWS * D_DIM * sizeof(__hip_bfloat16));
    float* pos = S + N_ROWS;

    ntx_normalize<<<N_ROWS / 4, 256, 0, stream>>>(z_i, z_j, zn, S);
    ntx_simtile<<<N_TILES, 256, 0, stream>>>(zn, S, pos);
    ntx_finalize<<<1, 1024, 0, stream>>>(S, pos, out);
}